// Round 1
// baseline (278.780 us; speedup 1.0000x reference)
//
#include <hip/hip_runtime.h>
#include <math.h>

#define D_    256
#define N_    1024
#define B_    8
#define H_    8
#define DV_   32
#define HID_  1024
#define ROWS_ (B_*N_)   // 8192

// ---------------------------------------------------------------- LayerNorm
__global__ __launch_bounds__(256) void k_ln(const float* __restrict__ x,
        const float* __restrict__ g, const float* __restrict__ b,
        float* __restrict__ pre) {
    int t = threadIdx.x;
    int lane = t & 63;
    int row = blockIdx.x * 4 + (t >> 6);
    const float4 v = ((const float4*)(x + row * D_))[lane];
    float s  = v.x + v.y + v.z + v.w;
    float sq = v.x*v.x + v.y*v.y + v.z*v.z + v.w*v.w;
    #pragma unroll
    for (int o = 32; o; o >>= 1) { s += __shfl_xor(s, o); sq += __shfl_xor(sq, o); }
    float m   = s * (1.0f / D_);
    float var = sq * (1.0f / D_) - m * m;
    float rs  = rsqrtf(var + 1e-5f);
    const float4 gv = ((const float4*)g)[lane];
    const float4 bv = ((const float4*)b)[lane];
    float4 o;
    o.x = (v.x - m) * rs * gv.x + bv.x;
    o.y = (v.y - m) * rs * gv.y + bv.y;
    o.z = (v.z - m) * rs * gv.z + bv.z;
    o.w = (v.w - m) * rs * gv.w + bv.w;
    ((float4*)(pre + row * D_))[lane] = o;
}

// ------------------------------------------------- generic fp32 tiled GEMM
// C[8192 x Ncols] = A[8192 x 256] @ Bm[256 x Ncols] (+bias)
__global__ __launch_bounds__(256) void k_gemm(const float* __restrict__ A,
        const float* __restrict__ Bm, const float* __restrict__ bias,
        float* __restrict__ C, int Ncols) {
    __shared__ float As[16][64];
    __shared__ float Bs[16][64];
    int t = threadIdx.x;
    int nBase = blockIdx.x * 64, rowBase = blockIdx.y * 64;
    int tx = t & 15, ty = t >> 4;
    int arow = t >> 2, ak = (t & 3) * 4;
    int bk = t >> 4, bn = (t & 15) * 4;
    float acc[4][4] = {};
    for (int kt = 0; kt < 256; kt += 16) {
        float4 av = *(const float4*)(A + (rowBase + arow) * 256 + kt + ak);
        As[ak+0][arow] = av.x; As[ak+1][arow] = av.y;
        As[ak+2][arow] = av.z; As[ak+3][arow] = av.w;
        float4 bv = make_float4(0.f, 0.f, 0.f, 0.f);
        if (nBase + bn < Ncols)
            bv = *(const float4*)(Bm + (kt + bk) * Ncols + nBase + bn);
        *(float4*)&Bs[bk][bn] = bv;
        __syncthreads();
        #pragma unroll
        for (int kk = 0; kk < 16; ++kk) {
            float4 a4 = *(const float4*)&As[kk][ty*4];
            float4 b4 = *(const float4*)&Bs[kk][tx*4];
            acc[0][0] += a4.x*b4.x; acc[0][1] += a4.x*b4.y; acc[0][2] += a4.x*b4.z; acc[0][3] += a4.x*b4.w;
            acc[1][0] += a4.y*b4.x; acc[1][1] += a4.y*b4.y; acc[1][2] += a4.y*b4.z; acc[1][3] += a4.y*b4.w;
            acc[2][0] += a4.z*b4.x; acc[2][1] += a4.z*b4.y; acc[2][2] += a4.z*b4.z; acc[2][3] += a4.z*b4.w;
            acc[3][0] += a4.w*b4.x; acc[3][1] += a4.w*b4.y; acc[3][2] += a4.w*b4.z; acc[3][3] += a4.w*b4.w;
        }
        __syncthreads();
    }
    int col = nBase + tx * 4;
    if (col < Ncols) {
        float4 bb = make_float4(0.f,0.f,0.f,0.f);
        if (bias) bb = *(const float4*)(bias + col);
        #pragma unroll
        for (int i = 0; i < 4; ++i) {
            float4 o;
            o.x = acc[i][0] + bb.x; o.y = acc[i][1] + bb.y;
            o.z = acc[i][2] + bb.z; o.w = acc[i][3] + bb.w;
            *(float4*)(C + (rowBase + ty*4 + i) * Ncols + col) = o;
        }
    }
}

// ------------------------------------------------------- scores argmax
// per block: one (b,h), 64 i's. thread: 4 i's, 1/16 of each j-chunk.
__global__ __launch_bounds__(256) void k_argmax(const float* __restrict__ q,
        const float* __restrict__ kv, int* __restrict__ idx) {
    __shared__ float4 kt[128][8];
    __shared__ float cval[64][16];
    __shared__ int   cidx[64][16];
    int t = threadIdx.x;
    int itile = blockIdx.x, h = blockIdx.y, b = blockIdx.z;
    int ig = t & 15, slice = t >> 4;
    int i0 = itile * 64 + ig * 4;
    const float4* q4  = (const float4*)q;
    const float4* kv4 = (const float4*)kv;
    float4 qr[4][8];
    #pragma unroll
    for (int ii = 0; ii < 4; ++ii)
        #pragma unroll
        for (int d4 = 0; d4 < 8; ++d4)
            qr[ii][d4] = q4[(b * N_ + i0 + ii) * 8 + d4];
    float best[4] = {-1e30f, -1e30f, -1e30f, -1e30f};
    int   bj[4]   = {0, 0, 0, 0};
    for (int chunk = 0; chunk < 8; ++chunk) {
        int jb = chunk * 128;
        #pragma unroll
        for (int m2 = 0; m2 < 4; ++m2) {
            int u = t + m2 * 256;
            int j = u >> 3, d4 = u & 7;
            kt[j][d4 ^ ((j >> 3) & 7)] =
                kv4[(b * N_ + jb + j) * 128 + h * 8 + d4];
        }
        __syncthreads();
        #pragma unroll
        for (int jj = 0; jj < 8; ++jj) {
            int j = slice * 8 + jj;
            int sw = (j >> 3) & 7;
            float4 kk[8];
            #pragma unroll
            for (int d4 = 0; d4 < 8; ++d4) kk[d4] = kt[j][d4 ^ sw];
            int jg = jb + j;
            #pragma unroll
            for (int ii = 0; ii < 4; ++ii) {
                float s = 0.f;
                #pragma unroll
                for (int d4 = 0; d4 < 8; ++d4) {
                    s += qr[ii][d4].x * kk[d4].x;
                    s += qr[ii][d4].y * kk[d4].y;
                    s += qr[ii][d4].z * kk[d4].z;
                    s += qr[ii][d4].w * kk[d4].w;
                }
                if (s > best[ii]) { best[ii] = s; bj[ii] = jg; }
            }
        }
        __syncthreads();
    }
    #pragma unroll
    for (int ii = 0; ii < 4; ++ii) {
        cval[ig*4 + ii][slice] = best[ii];
        cidx[ig*4 + ii][slice] = bj[ii];
    }
    __syncthreads();
    if (t < 64) {
        float bv = cval[t][0]; int bi = cidx[t][0];
        #pragma unroll
        for (int s = 1; s < 16; ++s) {
            float v = cval[t][s]; int j2 = cidx[t][s];
            if (v > bv || (v == bv && j2 < bi)) { bv = v; bi = j2; }
        }
        idx[(b * H_ + h) * N_ + itile * 64 + t] = bi;
    }
}

// ------------------------------------------------- fused RN tail
// gather v -> LN(32) -> head-sum -> inner GEMM -> gelu -> outer GEMM -> +bias+x
__global__ __launch_bounds__(256) void k_rn(const float* __restrict__ kv,
        const int* __restrict__ idx, const float* __restrict__ res,
        const float* __restrict__ x, const float* __restrict__ w_inner,
        const float* __restrict__ b_inner, const float* __restrict__ w_outer,
        const float* __restrict__ b_outer, const float* __restrict__ g,
        const float* __restrict__ bb, float* __restrict__ out) {
    __shared__ float rel[16][8][32];
    __shared__ float psum[16][64];
    __shared__ float mid[16][512];
    int t = threadIdx.x;
    int rowBase = blockIdx.x * 16;
    // gather hard-selected v rows
    {
        int p = t >> 1, half = t & 1;
        int r = p >> 3, h = p & 7;
        int bn = rowBase + r;
        int b = bn >> 10, i = bn & 1023;
        int j = idx[(b * H_ + h) * N_ + i];
        const float4* src = (const float4*)kv + (b * N_ + j) * 128 + 64 + h * 8 + half * 4;
        float4* dst = (float4*)&rel[r][h][half * 16];
        #pragma unroll
        for (int w = 0; w < 4; ++w) dst[w] = src[w];
    }
    __syncthreads();
    // LayerNorm over DV=32 per (row, head)
    if (t < 128) {
        int r = t >> 3, h = t & 7;
        float* v = rel[r][h];
        float s = 0.f, sq = 0.f;
        #pragma unroll
        for (int d = 0; d < 32; ++d) { float a = v[d]; s += a; sq += a * a; }
        float m = s * (1.f/32.f), var = sq * (1.f/32.f) - m * m;
        float rs = rsqrtf(var + 1e-5f);
        #pragma unroll
        for (int d = 0; d < 32; ++d) v[d] = (v[d] - m) * rs * g[d] + bb[d];
    }
    __syncthreads();
    // head-sum + 8*residual
    for (int e = t; e < 512; e += 256) {
        int r = e >> 5, d = e & 31;
        float s = 0.f;
        #pragma unroll
        for (int h = 0; h < 8; ++h) s += rel[r][h][d];
        psum[r][d] = s;
        psum[r][32 + d] = 8.f * res[(rowBase + r) * 32 + d];
    }
    __syncthreads();

    float oacc[4][4] = {};   // [r][c-chunk]
    int cBase = t & 63;
    int rO = (t >> 6) * 4;
    int cI = t & 127;
    int rI = (t >> 7) * 8;

    for (int halfk = 0; halfk < 2; ++halfk) {
        // inner GEMM (K=64) + gelu into mid[16][512]
        float iacc[4][8] = {};
        for (int k4 = 0; k4 < 16; ++k4) {
            float4 pv[8];
            #pragma unroll
            for (int rr = 0; rr < 8; ++rr)
                pv[rr] = *(const float4*)&psum[rI + rr][k4 * 4];
            #pragma unroll
            for (int mc = 0; mc < 4; ++mc) {
                int c = halfk * 512 + cI + 128 * mc;
                float w0 = w_inner[(k4*4 + 0) * HID_ + c];
                float w1 = w_inner[(k4*4 + 1) * HID_ + c];
                float w2 = w_inner[(k4*4 + 2) * HID_ + c];
                float w3 = w_inner[(k4*4 + 3) * HID_ + c];
                #pragma unroll
                for (int rr = 0; rr < 8; ++rr)
                    iacc[mc][rr] += pv[rr].x*w0 + pv[rr].y*w1 + pv[rr].z*w2 + pv[rr].w*w3;
            }
        }
        #pragma unroll
        for (int mc = 0; mc < 4; ++mc) {
            int c = halfk * 512 + cI + 128 * mc;
            float bi = 8.f * b_inner[c];
            #pragma unroll
            for (int rr = 0; rr < 8; ++rr) {
                float v = iacc[mc][rr] + bi;
                mid[rI + rr][cI + 128 * mc] = 0.5f * v * (1.f + erff(v * 0.70710678118f));
            }
        }
        __syncthreads();
        // outer GEMM partial over this k-half
        for (int k4 = 0; k4 < 128; ++k4) {
            float4 mv[4];
            #pragma unroll
            for (int rr = 0; rr < 4; ++rr)
                mv[rr] = *(const float4*)&mid[rO + rr][k4 * 4];
            int kk = halfk * 512 + k4 * 4;
            #pragma unroll
            for (int mc = 0; mc < 4; ++mc) {
                int c = cBase + 64 * mc;
                float w0 = w_outer[(kk + 0) * 256 + c];
                float w1 = w_outer[(kk + 1) * 256 + c];
                float w2 = w_outer[(kk + 2) * 256 + c];
                float w3 = w_outer[(kk + 3) * 256 + c];
                #pragma unroll
                for (int rr = 0; rr < 4; ++rr)
                    oacc[rr][mc] += mv[rr].x*w0 + mv[rr].y*w1 + mv[rr].z*w2 + mv[rr].w*w3;
            }
        }
        __syncthreads();
    }
    // epilogue: + b_outer + x
    #pragma unroll
    for (int mc = 0; mc < 4; ++mc) {
        int c = cBase + 64 * mc;
        float bo = b_outer[c];
        #pragma unroll
        for (int rr = 0; rr < 4; ++rr) {
            int bn = rowBase + rO + rr;
            out[bn * 256 + c] = oacc[rr][mc] + bo + x[bn * 256 + c];
        }
    }
}

extern "C" void kernel_launch(void* const* d_in, const int* in_sizes, int n_in,
                              void* d_out, int out_size, void* d_ws, size_t ws_size,
                              hipStream_t stream) {
    const float* x        = (const float*)d_in[0];
    const float* w_q      = (const float*)d_in[1];
    const float* w_kv     = (const float*)d_in[2];
    const float* ln_out_g = (const float*)d_in[3];
    const float* ln_out_b = (const float*)d_in[4];
    const float* ln_rel_g = (const float*)d_in[5];
    const float* ln_rel_b = (const float*)d_in[6];
    const float* w_down   = (const float*)d_in[7];
    const float* b_down   = (const float*)d_in[8];
    const float* w_inner  = (const float*)d_in[9];
    const float* b_inner  = (const float*)d_in[10];
    const float* w_outer  = (const float*)d_in[11];
    const float* b_outer  = (const float*)d_in[12];
    float* out = (float*)d_out;

    float* ws     = (float*)d_ws;
    float* pre    = ws;                      // 8192*256  = 2097152
    float* qbuf   = pre + 2097152;           // 8192*32   = 262144
    float* kvbuf  = qbuf + 262144;           // 8192*512  = 4194304
    float* resbuf = kvbuf + 4194304;         // 8192*32   = 262144
    int*   idxbuf = (int*)(resbuf + 262144); // 64*1024   = 65536 ints

    k_ln<<<2048, 256, 0, stream>>>(x, ln_out_g, ln_out_b, pre);
    k_gemm<<<dim3(8, 128), 256, 0, stream>>>(pre, w_kv, nullptr, kvbuf, 512);
    k_gemm<<<dim3(1, 128), 256, 0, stream>>>(pre, w_q, nullptr, qbuf, 32);
    k_gemm<<<dim3(1, 128), 256, 0, stream>>>(x, w_down, b_down, resbuf, 32);
    k_argmax<<<dim3(16, 8, 8), 256, 0, stream>>>(qbuf, kvbuf, idxbuf);
    k_rn<<<512, 256, 0, stream>>>(kvbuf, idxbuf, resbuf, x, w_inner, b_inner,
                                  w_outer, b_outer, ln_rel_g, ln_rel_b, out);
}